// Round 2
// baseline (40220.828 us; speedup 1.0000x reference)
//
#include <hip/hip_runtime.h>
#include <math.h>

#define Tn 1024
#define Bn 256
#define Hn 120
#define Ln 4
#define RCn 15            // cell-chunks per layer (8 cells each)
#define NBC 4             // batch-chunks (64 each)
#define BPL (RCn*NBC)     // 60 blocks per layer
#define NBLK (Ln*BPL)     // 240 blocks total
#define Dd 8              // ring depth (power of 2)

// Device-global scratch: no dependence on ws_size (R1 crash suspect #1).
// Protocol never reads a ring slot before writing it in the same call, so
// stale data across graph replays is harmless; g_progress/g_abort re-init'd
// by init_kernel every call.
__device__ float g_ring[(size_t)Ln * Dd * Hn * Bn];  // [l][slot][k][b]
__device__ int   g_progress[NBLK];
__device__ int   g_abort;

__global__ __launch_bounds__(256) void init_kernel(float* __restrict__ out,
                                                   const float* __restrict__ blin) {
    int idx = blockIdx.x * 256 + threadIdx.x;
    if (idx < Tn * Bn) out[idx] = blin[0];
    if (idx < NBLK)    g_progress[idx] = -0x40000000;
    if (idx == 0)      g_abort = 0;
}

__device__ __forceinline__ float sigm(float v) { return 1.0f / (1.0f + expf(-v)); }

// Bounded spin: ~6.5ms max per wait, then set abort so everyone fails fast
// (wrong answer beats a dead container — R1 crash suspect #2).
__device__ __forceinline__ void spin_wait(int pid, int tgt) {
    int guard = 0;
    while (__hip_atomic_load(&g_progress[pid], __ATOMIC_ACQUIRE,
                             __HIP_MEMORY_SCOPE_AGENT) < tgt) {
        __builtin_amdgcn_s_sleep(4);
        if ((++guard & 255) == 0) {
            if (guard > 60000) {
                __hip_atomic_store(&g_abort, 1, __ATOMIC_RELAXED, __HIP_MEMORY_SCOPE_AGENT);
                break;
            }
            if (__hip_atomic_load(&g_abort, __ATOMIC_RELAXED, __HIP_MEMORY_SCOPE_AGENT))
                break;
        }
    }
}

// Persistent pipelined LSTM.
// Block (l, rc, bc): layer l, cells [rc*8, rc*8+8), batch [bc*64, bc*64+64).
// Wave w owns cells rc*8 + 2w, +1; lane = batch element within the bc slice.
// progress[blk] = last completed superstep s = l + t.
// Deps of (l,t): same-layer peers @ s-1, layer below @ s-1, layer above
// (overwrite guard for slot reuse) @ s-Dd+1.
__global__ __launch_bounds__(256, 1) void lstm_kernel(
    const float* __restrict__ x,    const float* __restrict__ h0,
    const float* __restrict__ c0,   const float* __restrict__ Wih0,
    const float* __restrict__ Wih,  const float* __restrict__ Whh,
    const float* __restrict__ bih,  const float* __restrict__ bhh,
    const float* __restrict__ Wlin, float* __restrict__ out)
{
    __shared__ float sh_hv[Hn * 64];   // own-layer h_{t-1}, [k][b]
    __shared__ float sh_hb[Hn * 64];   // below-layer h_t,  [k][b]
    __shared__ float sh_part[4 * 64];  // layer-3 Wlin partials per wave

    const int bx   = blockIdx.x;
    const int l    = bx / BPL;
    const int rem  = bx % BPL;
    const int rc   = rem / NBC;
    const int bc   = rem % NBC;
    const int tid  = threadIdx.x;
    const int wv   = tid >> 6;
    const int lane = tid & 63;
    const int bco  = bc * 64;
    const int bg   = bco + lane;            // global batch index
    const int cell0 = rc * 8 + wv * 2;      // first of this wave's 2 cells

    // 8 gate rows: r = g*2 + p -> row g*Hn + cell0 + p (gate order i,f,g,o)
    int rows[8];
    #pragma unroll
    for (int g = 0; g < 4; ++g)
        #pragma unroll
        for (int p = 0; p < 2; ++p)
            rows[g * 2 + p] = __builtin_amdgcn_readfirstlane(g * Hn + cell0 + p);

    float bias[8];
    #pragma unroll
    for (int r = 0; r < 8; ++r)
        bias[r] = bih[l * 4 * Hn + rows[r]] + bhh[l * 4 * Hn + rows[r]];

    float w0[8];
    if (l == 0) {
        #pragma unroll
        for (int r = 0; r < 8; ++r) w0[r] = Wih0[rows[r]];
    }
    float wl[2] = {0.f, 0.f};
    if (l == 3) {
        #pragma unroll
        for (int p = 0; p < 2; ++p) wl[p] = Wlin[cell0 + p];
    }

    float cst[2];
    #pragma unroll
    for (int p = 0; p < 2; ++p) cst[p] = c0[(l * Bn + bg) * Hn + cell0 + p];

    // prefill slot(t=-1) == 0 with h0
    #pragma unroll
    for (int p = 0; p < 2; ++p)
        g_ring[((size_t)(l * Dd + 0) * Hn + cell0 + p) * Bn + bg] =
            h0[(l * Bn + bg) * Hn + cell0 + p];

    __threadfence();
    __syncthreads();
    if (tid == 0)
        __hip_atomic_store(&g_progress[bx], l - 1, __ATOMIC_RELEASE,
                           __HIP_MEMORY_SCOPE_AGENT);

    const float* WhhL = Whh + (size_t)l * 4 * Hn * Hn;
    const float* WihL = (l > 0) ? (Wih + (size_t)(l - 1) * 4 * Hn * Hn) : Whh;

    for (int t = 0; t < Tn; ++t) {
        const int s   = l + t;
        const int st  = (t + 1) & (Dd - 1);  // slot(t)   (being written)
        const int stp = t & (Dd - 1);        // slot(t-1) (own prev h)

        if (tid < RCn) {
            spin_wait(l * BPL + tid * NBC + bc, s - 1);
        } else if (tid >= 16 && tid < 16 + RCn) {
            if (l > 0) spin_wait((l - 1) * BPL + (tid - 16) * NBC + bc, s - 1);
        } else if (tid >= 32 && tid < 32 + RCn) {
            if (l < 3) spin_wait((l + 1) * BPL + (tid - 32) * NBC + bc, s - Dd + 1);
        }
        __syncthreads();

        // ---- stage h vectors into LDS (one coalesced 256B row per wave-step)
        {
            const float* hs = g_ring + (size_t)(l * Dd + stp) * Hn * Bn + bco;
            #pragma unroll
            for (int j = 0; j < (Hn * 64) / 256; ++j) {
                int f = j * 256 + tid;
                sh_hv[f] = hs[(f >> 6) * Bn + (f & 63)];
            }
            if (l > 0) {
                const float* bs = g_ring + (size_t)((l - 1) * Dd + st) * Hn * Bn + bco;
                #pragma unroll
                for (int j = 0; j < (Hn * 64) / 256; ++j) {
                    int f = j * 256 + tid;
                    sh_hb[f] = bs[(f >> 6) * Bn + (f & 63)];
                }
            }
        }
        __syncthreads();

        float acc[8];
        #pragma unroll
        for (int r = 0; r < 8; ++r) acc[r] = bias[r];

        if (l == 0) {
            float xv = x[t * Bn + bg];
            #pragma unroll
            for (int r = 0; r < 8; ++r) acc[r] = fmaf(w0[r], xv, acc[r]);
        } else {
            #pragma unroll
            for (int kb = 0; kb < Hn; kb += 24) {
                float hk[24];
                #pragma unroll
                for (int kk = 0; kk < 24; ++kk) hk[kk] = sh_hb[(kb + kk) * 64 + lane];
                #pragma unroll
                for (int r = 0; r < 8; ++r) {
                    const float* wr = WihL + rows[r] * Hn + kb;  // wave-uniform -> s_load
                    #pragma unroll
                    for (int kk = 0; kk < 24; ++kk)
                        acc[r] = fmaf(wr[kk], hk[kk], acc[r]);
                }
            }
        }
        #pragma unroll
        for (int kb = 0; kb < Hn; kb += 24) {
            float hk[24];
            #pragma unroll
            for (int kk = 0; kk < 24; ++kk) hk[kk] = sh_hv[(kb + kk) * 64 + lane];
            #pragma unroll
            for (int r = 0; r < 8; ++r) {
                const float* wr = WhhL + rows[r] * Hn + kb;      // wave-uniform -> s_load
                #pragma unroll
                for (int kk = 0; kk < 24; ++kk)
                    acc[r] = fmaf(wr[kk], hk[kk], acc[r]);
            }
        }

        // ---- cell update + publish h
        float pout = 0.f;
        #pragma unroll
        for (int p = 0; p < 2; ++p) {
            float ig = sigm(acc[0 * 2 + p]);
            float fg = sigm(acc[1 * 2 + p]);
            float gg = tanhf(acc[2 * 2 + p]);
            float og = sigm(acc[3 * 2 + p]);
            float cn = fmaf(fg, cst[p], ig * gg);
            cst[p] = cn;
            float hn = og * tanhf(cn);
            g_ring[((size_t)(l * Dd + st) * Hn + cell0 + p) * Bn + bg] = hn;
            if (l == 3) pout = fmaf(wl[p], hn, pout);
        }
        if (l == 3) sh_part[wv * 64 + lane] = pout;

        __threadfence();
        __syncthreads();
        if (l == 3 && tid < 64) {
            float sum = sh_part[tid] + sh_part[64 + tid] +
                        sh_part[128 + tid] + sh_part[192 + tid];
            atomicAdd(&out[t * Bn + bco + tid], sum);
        }
        if (tid == 0)
            __hip_atomic_store(&g_progress[bx], s, __ATOMIC_RELEASE,
                               __HIP_MEMORY_SCOPE_AGENT);
    }
}

extern "C" void kernel_launch(void* const* d_in, const int* in_sizes, int n_in,
                              void* d_out, int out_size, void* d_ws, size_t ws_size,
                              hipStream_t stream) {
    const float* x    = (const float*)d_in[0];
    const float* h0   = (const float*)d_in[1];
    const float* c0   = (const float*)d_in[2];
    const float* Wih0 = (const float*)d_in[3];
    const float* Wih  = (const float*)d_in[4];
    const float* Whh  = (const float*)d_in[5];
    const float* bih  = (const float*)d_in[6];
    const float* bhh  = (const float*)d_in[7];
    const float* Wlin = (const float*)d_in[8];
    const float* blin = (const float*)d_in[9];
    float* out = (float*)d_out;

    hipLaunchKernelGGL(init_kernel, dim3((Tn * Bn + 255) / 256), dim3(256), 0, stream,
                       out, blin);
    hipLaunchKernelGGL(lstm_kernel, dim3(NBLK), dim3(256), 0, stream,
                       x, h0, c0, Wih0, Wih, Whh, bih, bhh, Wlin, out);
}

// Round 4
// 25696.982 us; speedup vs baseline: 1.5652x; 1.5652x over previous
//
#include <hip/hip_runtime.h>
#include <math.h>

#define Tn 1024
#define Bn 256
#define Hn 120
#define Ln 4
#define RCn 15            // cell-chunks per layer (8 cells each)
#define NBC 4             // batch-chunks (64 each)
#define BPL (RCn*NBC)     // 60 blocks per layer
#define NBLK (Ln*BPL)     // 240 blocks total
#define Dd 8              // ring depth (power of 2)

// Cross-block data goes ONLY through relaxed SYSTEM-scope atomics
// (-> global_load/store sc0 sc1: per-access coherence at the Infinity
// Cache, bypassing the 8 non-coherent per-XCD L2s). NO acquire/release
// fences anywhere in the steady loop: on gfx950 those are full-L2
// inv/writeback (R2's 70us/superstep disaster), while relaxed AGENT-scope
// atomics without fences are L2-local -> invisible cross-XCD (R3's
// livelock/timeout). System-relaxed is the per-access middle path.
__device__ float g_ring[(size_t)Ln * Dd * Hn * Bn];  // [l][slot][k][b]
__device__ int   g_progress[NBLK];
__device__ int   g_abort;

__global__ __launch_bounds__(256) void init_kernel(float* __restrict__ out,
                                                   const float* __restrict__ blin) {
    int idx = blockIdx.x * 256 + threadIdx.x;
    if (idx < Tn * Bn) out[idx] = blin[0];
    if (idx < NBLK)    g_progress[idx] = -0x40000000;  // kernel-end flush publishes
    if (idx == 0)      g_abort = 0;
}

__device__ __forceinline__ float sigm(float v) { return 1.0f / (1.0f + expf(-v)); }

__device__ __forceinline__ float ring_ld(const float* p) {
    return __hip_atomic_load((float*)p, __ATOMIC_RELAXED, __HIP_MEMORY_SCOPE_SYSTEM);
}
__device__ __forceinline__ void ring_st(float* p, float v) {
    __hip_atomic_store(p, v, __ATOMIC_RELAXED, __HIP_MEMORY_SCOPE_SYSTEM);
}

// Bounded spin, system-scope polls. First timeout (~20ms) sets global abort
// (RMW -> guaranteed visible) and marks this thread dead so it skips ALL
// later waits: worst case ~25ms of wrong answers, never a dead container.
__device__ __forceinline__ void spin_wait(int pid, int tgt, int& dead) {
    if (dead) return;
    int guard = 0;
    while (__hip_atomic_load(&g_progress[pid], __ATOMIC_RELAXED,
                             __HIP_MEMORY_SCOPE_SYSTEM) < tgt) {
        __builtin_amdgcn_s_sleep(1);
        if ((++guard & 63) == 0) {
            if (__hip_atomic_load(&g_abort, __ATOMIC_RELAXED,
                                  __HIP_MEMORY_SCOPE_SYSTEM)) { dead = 1; return; }
            if (guard > 60000) { atomicExch(&g_abort, 1); dead = 1; return; }
        }
    }
}

// Persistent pipelined LSTM.
// Block (l, rc, bc): layer l, cells [rc*8, rc*8+8), batch [bc*64, bc*64+64).
// Wave w owns cells rc*8 + 2w, +1; lane = batch element within the bc slice.
// progress[blk] = last completed superstep s = l + t.
// Deps of (l,t): same-layer peers @ s-1, layer below @ s-1, layer above
// (slot-overwrite guard) @ s-Dd+1.  (Slot arithmetic re-verified exact.)
__global__ __launch_bounds__(256, 1) void lstm_kernel(
    const float* __restrict__ x,    const float* __restrict__ h0,
    const float* __restrict__ c0,   const float* __restrict__ Wih0,
    const float* __restrict__ Wih,  const float* __restrict__ Whh,
    const float* __restrict__ bih,  const float* __restrict__ bhh,
    const float* __restrict__ Wlin, float* __restrict__ out)
{
    __shared__ float sh_hv[Hn * 64];   // own-layer h_{t-1}, [k][b]
    __shared__ float sh_hb[Hn * 64];   // below-layer h_t,  [k][b]
    __shared__ float sh_part[4 * 64];  // layer-3 Wlin partials per wave

    const int bx   = blockIdx.x;
    const int l    = bx / BPL;
    const int rem  = bx % BPL;
    const int rc   = rem / NBC;
    const int bc   = rem % NBC;
    const int tid  = threadIdx.x;
    const int wv   = tid >> 6;
    const int lane = tid & 63;
    const int bco  = bc * 64;
    const int bg   = bco + lane;            // global batch index
    const int cell0 = rc * 8 + wv * 2;      // first of this wave's 2 cells
    int dead = 0;

    // 8 gate rows: r = g*2 + p -> row g*Hn + cell0 + p (gate order i,f,g,o)
    int rows[8];
    #pragma unroll
    for (int g = 0; g < 4; ++g)
        #pragma unroll
        for (int p = 0; p < 2; ++p)
            rows[g * 2 + p] = __builtin_amdgcn_readfirstlane(g * Hn + cell0 + p);

    float bias[8];
    #pragma unroll
    for (int r = 0; r < 8; ++r)
        bias[r] = bih[l * 4 * Hn + rows[r]] + bhh[l * 4 * Hn + rows[r]];

    float w0[8];
    if (l == 0) {
        #pragma unroll
        for (int r = 0; r < 8; ++r) w0[r] = Wih0[rows[r]];
    }
    float wl[2] = {0.f, 0.f};
    if (l == 3) {
        #pragma unroll
        for (int p = 0; p < 2; ++p) wl[p] = Wlin[cell0 + p];
    }

    float cst[2];
    #pragma unroll
    for (int p = 0; p < 2; ++p) cst[p] = c0[(l * Bn + bg) * Hn + cell0 + p];

    // prefill slot(t=-1) == 0 with h0 (coherent stores)
    #pragma unroll
    for (int p = 0; p < 2; ++p)
        ring_st(&g_ring[((size_t)(l * Dd + 0) * Hn + cell0 + p) * Bn + bg],
                h0[(l * Bn + bg) * Hn + cell0 + p]);

    asm volatile("s_waitcnt vmcnt(0)" ::: "memory");  // own sc0sc1 stores at MALL
    __syncthreads();                                   // whole block drained
    if (tid == 0) atomicExch(&g_progress[bx], l - 1);  // RMW publish

    const float* WhhL = Whh + (size_t)l * 4 * Hn * Hn;
    const float* WihL = (l > 0) ? (Wih + (size_t)(l - 1) * 4 * Hn * Hn) : Whh;

    for (int t = 0; t < Tn; ++t) {
        const int s   = l + t;
        const int st  = (t + 1) & (Dd - 1);  // slot(t)   (being written)
        const int stp = t & (Dd - 1);        // slot(t-1) (own prev h)

        if (tid < RCn) {
            spin_wait(l * BPL + tid * NBC + bc, s - 1, dead);
        } else if (tid >= 16 && tid < 16 + RCn) {
            if (l > 0) spin_wait((l - 1) * BPL + (tid - 16) * NBC + bc, s - 1, dead);
        } else if (tid >= 32 && tid < 32 + RCn) {
            if (l < 3) spin_wait((l + 1) * BPL + (tid - 32) * NBC + bc, s - Dd + 1, dead);
        }
        __syncthreads();

        // ---- stage h vectors into LDS (coherent, coalesced: lane-stride-1)
        {
            const float* hs = g_ring + (size_t)(l * Dd + stp) * Hn * Bn + bco;
            #pragma unroll
            for (int j = 0; j < (Hn * 64) / 256; ++j) {
                int f = j * 256 + tid;
                sh_hv[f] = ring_ld(&hs[(f >> 6) * Bn + (f & 63)]);
            }
            if (l > 0) {
                const float* bs = g_ring + (size_t)((l - 1) * Dd + st) * Hn * Bn + bco;
                #pragma unroll
                for (int j = 0; j < (Hn * 64) / 256; ++j) {
                    int f = j * 256 + tid;
                    sh_hb[f] = ring_ld(&bs[(f >> 6) * Bn + (f & 63)]);
                }
            }
        }
        __syncthreads();

        float acc[8];
        #pragma unroll
        for (int r = 0; r < 8; ++r) acc[r] = bias[r];

        if (l == 0) {
            float xv = x[t * Bn + bg];
            #pragma unroll
            for (int r = 0; r < 8; ++r) acc[r] = fmaf(w0[r], xv, acc[r]);
        } else {
            #pragma unroll
            for (int kb = 0; kb < Hn; kb += 24) {
                float hk[24];
                #pragma unroll
                for (int kk = 0; kk < 24; ++kk) hk[kk] = sh_hb[(kb + kk) * 64 + lane];
                #pragma unroll
                for (int r = 0; r < 8; ++r) {
                    const float* wr = WihL + rows[r] * Hn + kb;  // wave-uniform -> s_load
                    #pragma unroll
                    for (int kk = 0; kk < 24; ++kk)
                        acc[r] = fmaf(wr[kk], hk[kk], acc[r]);
                }
            }
        }
        #pragma unroll
        for (int kb = 0; kb < Hn; kb += 24) {
            float hk[24];
            #pragma unroll
            for (int kk = 0; kk < 24; ++kk) hk[kk] = sh_hv[(kb + kk) * 64 + lane];
            #pragma unroll
            for (int r = 0; r < 8; ++r) {
                const float* wr = WhhL + rows[r] * Hn + kb;      // wave-uniform -> s_load
                #pragma unroll
                for (int kk = 0; kk < 24; ++kk)
                    acc[r] = fmaf(wr[kk], hk[kk], acc[r]);
            }
        }

        // ---- cell update + publish h (coherent stores)
        float pout = 0.f;
        #pragma unroll
        for (int p = 0; p < 2; ++p) {
            float ig = sigm(acc[0 * 2 + p]);
            float fg = sigm(acc[1 * 2 + p]);
            float gg = tanhf(acc[2 * 2 + p]);
            float og = sigm(acc[3 * 2 + p]);
            float cn = fmaf(fg, cst[p], ig * gg);
            cst[p] = cn;
            float hn = og * tanhf(cn);
            ring_st(&g_ring[((size_t)(l * Dd + st) * Hn + cell0 + p) * Bn + bg], hn);
            if (l == 3) pout = fmaf(wl[p], hn, pout);
        }
        if (l == 3) sh_part[wv * 64 + lane] = pout;

        asm volatile("s_waitcnt vmcnt(0)" ::: "memory");  // own ring stores at MALL
        __syncthreads();                                   // whole block drained
        if (l == 3 && tid < 64) {
            float sum = sh_part[tid] + sh_part[64 + tid] +
                        sh_part[128 + tid] + sh_part[192 + tid];
            atomicAdd(&out[t * Bn + bco + tid], sum);
        }
        if (tid == 0) atomicExch(&g_progress[bx], s);      // RMW publish
    }
}

extern "C" void kernel_launch(void* const* d_in, const int* in_sizes, int n_in,
                              void* d_out, int out_size, void* d_ws, size_t ws_size,
                              hipStream_t stream) {
    const float* x    = (const float*)d_in[0];
    const float* h0   = (const float*)d_in[1];
    const float* c0   = (const float*)d_in[2];
    const float* Wih0 = (const float*)d_in[3];
    const float* Wih  = (const float*)d_in[4];
    const float* Whh  = (const float*)d_in[5];
    const float* bih  = (const float*)d_in[6];
    const float* bhh  = (const float*)d_in[7];
    const float* Wlin = (const float*)d_in[8];
    const float* blin = (const float*)d_in[9];
    float* out = (float*)d_out;

    hipLaunchKernelGGL(init_kernel, dim3((Tn * Bn + 255) / 256), dim3(256), 0, stream,
                       out, blin);
    hipLaunchKernelGGL(lstm_kernel, dim3(NBLK), dim3(256), 0, stream,
                       x, h0, c0, Wih0, Wih, Whh, bih, bhh, Wlin, out);
}